// Round 12
// baseline (33.207 us; speedup 1.0000x reference)
//
#include <hip/hip_runtime.h>

// ROI max-pool (aspect-preserving "OCR" variant) — separable two-phase, v9.
// feats: (B=4, C=128, H=64, W=512) fp32
// rois:  (N, 5) fp32 = [batch, x1, y1, x2, y2] image coords, spatial scale 0.25
// out:   (N, C, PH=8, PW=32) fp32
//
// Block = 64 threads (1 wave) = 32 w-lanes x 2 cslots, one (roi, channel-
// group of 8, ph-HALF of 4 bins). The 4 ph bins run SEQUENTIALLY, reusing
// one 3.7 KB LDS buffer: boundary h-rows shared by adjacent bins are
// re-read from hot L2 instead of a second HBM fetch (saves ~6/7 of the
// boundary double-fetch ≈ 20 MB), and ROI setup + per-lane bin bounds are
// amortized over 4 bins. 8192 blocks = 32 single-wave blocks/CU residency.
// Phase 1: rowmax over h -> LDS (float4, 4-aligned window). Phase 2: w-max
// from LDS as a fixed 8-wide masked unroll (bin width <= 5).

#define PHB 8
#define PWB 32
#define CHB 8           // channels per block
#define WST 116         // staged width cap: ceil(32*bsw) <= 108, +3 align
#define BLK 64

static __device__ __forceinline__ float4 max4(float4 a, float4 b) {
    float4 r;
    r.x = fmaxf(a.x, b.x); r.y = fmaxf(a.y, b.y);
    r.z = fmaxf(a.z, b.z); r.w = fmaxf(a.w, b.w);
    return r;
}

__global__ __launch_bounds__(BLK) void ocr_roi_pool_kernel(
    const float* __restrict__ feats,
    const float* __restrict__ rois,
    float* __restrict__ out,
    int Cc, int Hc, int Wc)
{
#pragma clang fp contract(off)
    __shared__ float smax[CHB * WST + 8];   // +8: phase-2 unroll over-read pad

    int b    = blockIdx.x;             // ((n*16 + cg)*2 + half)
    int half = b & 1;
    int cg   = (b >> 1) & 15;
    int n    = b >> 5;
    int c0   = cg * CHB;
    int ph0  = half * 4;

    // ---- ROI params: block-uniform -> scalar (once per 4 ph bins) ----
    const float* r = rois + n * 5;
    int rb  = (int)r[0];
    int rsw = (int)floorf(r[1] * 0.25f + 0.5f);
    int rsh = (int)floorf(r[2] * 0.25f + 0.5f);
    int rew = (int)floorf(r[3] * 0.25f + 0.5f);
    int reh = (int)floorf(r[4] * 0.25f + 0.5f);

    int roi_w = max(rew - rsw + 1, 1);
    int roi_h = max(reh - rsh + 1, 1);
    int rpw   = (PHB * roi_w + roi_h - 1) / roi_h;

    float bsh = (float)roi_h / (float)PHB;
    float bsw = (float)roi_w / (float)rpw;

    // staged w-window: covers every NON-PAD bin's reads; 4-aligned base.
    int wlo = min(max(rsw, 0), Wc);
    int whi = (int)ceilf((float)PWB * bsw) + rsw;
    whi = min(whi, rew + 4);
    whi = min(max(whi, 0), Wc);
    int wlo_al = wlo & ~3;
    int wwid = min(whi - wlo_al, WST);

    int t      = threadIdx.x;
    int lane_w = t & 31;
    int cslot  = t >> 5;               // 0..1
    int wp4    = lane_w * 4;           // this lane's 4-column slot

    const int plane_stride = Hc * Wc;  // 32768

    // ---- per-lane w-bin bounds (uniform across ph) ----
    int ws = (int)floorf((float)lane_w * bsw) + rsw;
    int we = (int)ceilf((float)(lane_w + 1) * bsw) + rsw;
    ws = min(max(ws, 0), Wc);
    we = min(max(we, 0), Wc);
    bool wzero = (ws >= rew) || (we <= ws);   // pad or empty-in-w
    int base = ws - wlo_al;            // >= 0
    int nw   = we - ws;                // 1..5 (bsw <= 3.375)

    const float* plane =
        feats + ((size_t)(rb * Cc + c0 + cslot) * Hc) * Wc;

    // ---- loop over this block's 4 ph bins, reusing LDS ----
    for (int dph = 0; dph < 4; ++dph) {
        int ph = ph0 + dph;
        int hs = (int)floorf((float)ph * bsh) + rsh;
        int he = (int)ceilf((float)(ph + 1) * bsh) + rsh;
        hs = min(max(hs, 0), Hc);
        he = min(max(he, 0), Hc);

        __syncthreads();               // guard LDS reuse (1-wave: cheap)

        // Phase 1: rowmax -> LDS (float4 loads, h unrolled x2)
        if (he > hs && wp4 < wwid) {
            float4 rm[4];
#pragma unroll
            for (int j = 0; j < 4; ++j)
                rm[j] = make_float4(-1e37f, -1e37f, -1e37f, -1e37f);
            for (int h = hs; h < he; h += 2) {
                int hb   = min(h + 1, he - 1);
                int offa = h  * Wc + wlo_al + wp4;   // 16B-aligned, in-row
                int offb = hb * Wc + wlo_al + wp4;
#pragma unroll
                for (int j = 0; j < 4; ++j) {
                    const float* pj = plane + (size_t)(2 * j) * plane_stride;
                    float4 va = *reinterpret_cast<const float4*>(pj + offa);
                    float4 vb = *reinterpret_cast<const float4*>(pj + offb);
                    rm[j] = max4(rm[j], max4(va, vb));
                }
            }
#pragma unroll
            for (int j = 0; j < 4; ++j)   // 464B row stride: 16B-aligned
                *reinterpret_cast<float4*>(&smax[(cslot + 2 * j) * WST + wp4]) = rm[j];
        }
        __syncthreads();

        // Phase 2: colmax from LDS (fixed 8-wide masked unroll), store
        bool zero = wzero || (he <= hs);
        size_t obase = (((size_t)n * Cc + c0 + cslot) * PHB + ph) * PWB + lane_w;
        if (zero) {
#pragma unroll
            for (int j = 0; j < 4; ++j)
                out[obase + (size_t)(2 * j) * (PHB * PWB)] = 0.0f;
        } else {
#pragma unroll
            for (int j = 0; j < 4; ++j) {
                const float* row = &smax[(cslot + 2 * j) * WST + base];
                float m = -1e37f;
#pragma unroll
                for (int i = 0; i < 8; ++i) {        // 8 independent ds_reads,
                    float v = row[i];                // masked beyond nw
                    m = (i < nw) ? fmaxf(m, v) : m;
                }
                out[obase + (size_t)(2 * j) * (PHB * PWB)] = m;
            }
        }
    }
}

extern "C" void kernel_launch(void* const* d_in, const int* in_sizes, int n_in,
                              void* d_out, int out_size, void* d_ws, size_t ws_size,
                              hipStream_t stream) {
    const float* feats = (const float*)d_in[0];
    const float* rois  = (const float*)d_in[1];
    float* out = (float*)d_out;

    const int Cc = 128, Hc = 64, Wc = 512;
    int nroi = in_sizes[1] / 5;
    int blocks = nroi * (Cc / CHB) * 2;   // (n, cg, ph-half) = 8192

    ocr_roi_pool_kernel<<<blocks, BLK, 0, stream>>>(feats, rois, out, Cc, Hc, Wc);
}

// Round 13
// 28.093 us; speedup vs baseline: 1.1820x; 1.1820x over previous
//
#include <hip/hip_runtime.h>

// ROI max-pool (aspect-preserving "OCR" variant) — separable two-phase, v10.
// feats: (B=4, C=128, H=64, W=512) fp32
// rois:  (N, 5) fp32 = [batch, x1, y1, x2, y2] image coords, spatial scale 0.25
// out:   (N, C, PH=8, PW=32) fp32
//
// Work item = (roi, ph, channel-group of 8), processed by 1 wave (R10's
// winning granularity). 8192 blocks x 4 grid-strided items each (stride
// 8192 -> the 4 items differ in n by 64: uncorrelated ROI sizes, so
// per-wave sums self-balance) — 4x fewer workgroup dispatches than R10.
// Phase 1: rowmax over h -> LDS (float4, 4-aligned window).
// Phase 2: w-max from LDS, fixed 8-wide masked unroll (bin width <= 5).

#define PHB 8
#define PWB 32
#define CHB 8           // channels per item
#define WST 116         // staged width cap: ceil(32*bsw) <= 108, +3 align
#define BLK 64
#define ITERS 4

static __device__ __forceinline__ float4 max4(float4 a, float4 b) {
    float4 r;
    r.x = fmaxf(a.x, b.x); r.y = fmaxf(a.y, b.y);
    r.z = fmaxf(a.z, b.z); r.w = fmaxf(a.w, b.w);
    return r;
}

__global__ __launch_bounds__(BLK) void ocr_roi_pool_kernel(
    const float* __restrict__ feats,
    const float* __restrict__ rois,
    float* __restrict__ out,
    int Cc, int Hc, int Wc, int nblk)
{
#pragma clang fp contract(off)
    __shared__ float smax[CHB * WST + 8];   // +8: phase-2 unroll over-read pad

    int t      = threadIdx.x;
    int lane_w = t & 31;
    int cslot  = t >> 5;               // 0..1
    int wp4    = lane_w * 4;           // this lane's 4-column slot
    const int plane_stride = Hc * Wc;  // 32768

    for (int it = 0; it < ITERS; ++it) {
        int b  = blockIdx.x + it * nblk;   // ((n*8 + ph)*16 + cg)
        int cg = b & 15;
        int ph = (b >> 4) & 7;
        int n  = b >> 7;
        int c0 = cg * CHB;

        // ---- ROI params: block-uniform -> scalar ----
        const float* r = rois + n * 5;
        int rb  = (int)r[0];
        int rsw = (int)floorf(r[1] * 0.25f + 0.5f);
        int rsh = (int)floorf(r[2] * 0.25f + 0.5f);
        int rew = (int)floorf(r[3] * 0.25f + 0.5f);
        int reh = (int)floorf(r[4] * 0.25f + 0.5f);

        int roi_w = max(rew - rsw + 1, 1);
        int roi_h = max(reh - rsh + 1, 1);
        int rpw   = (PHB * roi_w + roi_h - 1) / roi_h;

        float bsh = (float)roi_h / (float)PHB;
        float bsw = (float)roi_w / (float)rpw;

        // h-range for this ph (uniform over block), exact reference math
        int hs = (int)floorf((float)ph * bsh) + rsh;
        int he = (int)ceilf((float)(ph + 1) * bsh) + rsh;
        hs = min(max(hs, 0), Hc);
        he = min(max(he, 0), Hc);

        // staged w-window: covers every NON-PAD bin's reads; 4-aligned base.
        int wlo = min(max(rsw, 0), Wc);
        int whi = (int)ceilf((float)PWB * bsw) + rsw;
        whi = min(whi, rew + 4);
        whi = min(max(whi, 0), Wc);
        int wlo_al = wlo & ~3;
        int wwid = min(whi - wlo_al, WST);

        __syncthreads();               // guard LDS reuse (1-wave: cheap)

        // ---- Phase 1: rowmax -> LDS (float4 loads, h unrolled x2) ----
        if (he > hs && wp4 < wwid) {
            const float* plane =
                feats + ((size_t)(rb * Cc + c0 + cslot) * Hc) * Wc;
            float4 rm[4];
#pragma unroll
            for (int j = 0; j < 4; ++j)
                rm[j] = make_float4(-1e37f, -1e37f, -1e37f, -1e37f);
            for (int h = hs; h < he; h += 2) {
                int hb   = min(h + 1, he - 1);
                int offa = h  * Wc + wlo_al + wp4;   // 16B-aligned, in-row
                int offb = hb * Wc + wlo_al + wp4;
#pragma unroll
                for (int j = 0; j < 4; ++j) {
                    const float* pj = plane + (size_t)(2 * j) * plane_stride;
                    float4 va = *reinterpret_cast<const float4*>(pj + offa);
                    float4 vb = *reinterpret_cast<const float4*>(pj + offb);
                    rm[j] = max4(rm[j], max4(va, vb));
                }
            }
#pragma unroll
            for (int j = 0; j < 4; ++j)   // 464B row stride: 16B-aligned
                *reinterpret_cast<float4*>(&smax[(cslot + 2 * j) * WST + wp4]) = rm[j];
        }
        __syncthreads();

        // ---- Phase 2: colmax from LDS (fixed 8-wide masked unroll) ----
        int ws = (int)floorf((float)lane_w * bsw) + rsw;
        int we = (int)ceilf((float)(lane_w + 1) * bsw) + rsw;
        ws = min(max(ws, 0), Wc);
        we = min(max(we, 0), Wc);

        bool pad   = (ws >= rew);
        bool empty = (he <= hs) || (we <= ws);

        size_t obase = (((size_t)n * Cc + c0 + cslot) * PHB + ph) * PWB + lane_w;
        if (pad || empty) {
#pragma unroll
            for (int j = 0; j < 4; ++j)
                out[obase + (size_t)(2 * j) * (PHB * PWB)] = 0.0f;
        } else {
            int base = ws - wlo_al;    // >= 0
            int nw   = we - ws;        // 1..5 (bsw <= 3.375)
#pragma unroll
            for (int j = 0; j < 4; ++j) {
                const float* row = &smax[(cslot + 2 * j) * WST + base];
                float m = -1e37f;
#pragma unroll
                for (int i = 0; i < 8; ++i) {        // 8 independent ds_reads,
                    float v = row[i];                // masked beyond nw
                    m = (i < nw) ? fmaxf(m, v) : m;
                }
                out[obase + (size_t)(2 * j) * (PHB * PWB)] = m;
            }
        }
    }
}

extern "C" void kernel_launch(void* const* d_in, const int* in_sizes, int n_in,
                              void* d_out, int out_size, void* d_ws, size_t ws_size,
                              hipStream_t stream) {
    const float* feats = (const float*)d_in[0];
    const float* rois  = (const float*)d_in[1];
    float* out = (float*)d_out;

    const int Cc = 128, Hc = 64, Wc = 512;
    int nroi  = in_sizes[1] / 5;
    int total = nroi * PHB * (Cc / CHB);   // 32768 items
    int nblk  = total / ITERS;             // 8192 workgroups

    ocr_roi_pool_kernel<<<nblk, BLK, 0, stream>>>(feats, rois, out, Cc, Hc, Wc, nblk);
}